// Round 14
// baseline (380.881 us; speedup 1.0000x reference)
//
#include <hip/hip_runtime.h>
#include <hip/hip_fp16.h>
#include <math.h>

// ---------------------------------------------------------------------------
// GATv2 x2 + mean-pool + linear, MI355X.
// R14: (1) fill/gemm1 blocks INTERLEAVED (24-block groups: 16 fill + 8 gemm;
//      24%8==0 keeps vb&7 == b&7 == XCD) so atomic-stall fill waves and
//      VALU gemm waves co-reside (R13: they ran serially, 61us = 50+12).
//      (2) aggregate: grid-stride waves (2048 blocks; ~6 nodes/wave) to kill
//      block-turnover underutilization (occ was ~65%).
//      (3) final fused into pool via last-block ticket (one fewer boundary).
// ---------------------------------------------------------------------------

#define ELLC    48
#define OVF_CAP 65536
#define ECHUNK  2048          // edges per fill virtual block

typedef int      vint4 __attribute__((ext_vector_type(4)));
typedef _Float16 half4 __attribute__((ext_vector_type(4)));

// ---------------- slim dual GEMM body: xl = X*Wl + bl (fp16), xr = X*Wr + br
#define GROWS 32
__device__ __forceinline__ void dual_gemm_slim(
    int bid, int t,
    const float* __restrict__ X,
    const float* __restrict__ Wl, const float* __restrict__ bl,
    const float* __restrict__ Wr, const float* __restrict__ br,
    _Float16* __restrict__ xl, float* __restrict__ xr, int n,
    float* xS) {
    int row0 = bid * GROWS;
    for (int i = t; i < GROWS * 16; i += 256) {
        int r = row0 + (i >> 4);
        float4 v = make_float4(0.f, 0.f, 0.f, 0.f);
        if (r < n) v = ((const float4*)(X + (size_t)r * 64))[i & 15];
        ((float4*)xS)[i] = v;
    }
    __syncthreads();
    int h  = t & 63;
    int rb = t >> 6;  // 0..3
    float accl[8], accr[8];
#pragma unroll
    for (int i = 0; i < 8; ++i) { accl[i] = 0.f; accr[i] = 0.f; }
#pragma unroll 4
    for (int d = 0; d < 64; ++d) {
        float wl = Wl[d * 64 + h];   // coalesced 256B, L2-hot
        float wr = Wr[d * 64 + h];
#pragma unroll
        for (int i = 0; i < 8; ++i) {
            float xv = xS[(rb + 4 * i) * 64 + d];  // wave-uniform broadcast
            accl[i] += xv * wl;
            accr[i] += xv * wr;
        }
    }
    float blv = bl[h], brv = br[h];
#pragma unroll
    for (int i = 0; i < 8; ++i) {
        int r = row0 + rb + 4 * i;
        if (r < n) {
            xl[(size_t)r * 64 + h] = (_Float16)(accl[i] + blv);  // 2B, coalesced
            xr[(size_t)r * 64 + h] = accr[i] + brv;
        }
    }
}

__global__ __launch_bounds__(256) void dual_gemm64_kernel(
    const float* __restrict__ X,
    const float* __restrict__ Wl, const float* __restrict__ bl,
    const float* __restrict__ Wr, const float* __restrict__ br,
    _Float16* __restrict__ xl, float* __restrict__ xr, int n) {
    __shared__ float xS[GROWS * 64];
    dual_gemm_slim(blockIdx.x, threadIdx.x, X, Wl, bl, Wr, br, xl, xr, n, xS);
}

// ---------------- interleaved: XCD-partitioned ELL fill + layer-1 GEMM ----
// 24-block groups: r = b%24. r<16 -> fill vb = (b/24)*16+r (vb&7 == b&7!);
// r>=16 -> gemm vg = (b/24)*8 + (r-16).
__global__ __launch_bounds__(256) void fill_gemm_kernel(
    const int* __restrict__ src, const int* __restrict__ dst,
    int* __restrict__ cnt, unsigned short* __restrict__ ell,
    int* __restrict__ novf, int* __restrict__ ovf_dst, int* __restrict__ ovf_src,
    int E, int N, int psize, int fb, int ggrid,
    const float* __restrict__ X,
    const float* __restrict__ Wl, const float* __restrict__ bl,
    const float* __restrict__ Wr, const float* __restrict__ br,
    _Float16* __restrict__ xl, float* __restrict__ xr) {
    __shared__ float xS[GROWS * 64];
    int b = blockIdx.x;
    int q = b / 24, r = b % 24;
    if (r >= 16) {
        int vg = q * 8 + (r - 16);
        if (vg < ggrid)
            dual_gemm_slim(vg, threadIdx.x, X, Wl, bl, Wr, br, xl, xr, N, xS);
        return;
    }
    int vb = q * 16 + r;
    if (vb >= fb) return;
    int t     = threadIdx.x;
    int chunk = vb >> 3;
    int p     = vb & 7;                   // partition == XCD (== b&7)
    int d0    = p * psize;
    int d1    = min(N, d0 + psize);
    int e0    = chunk * ECHUNK;
    int e1    = min(E, e0 + ECHUNK);
    int nq    = (e1 - e0) >> 2;
    const vint4* dst4 = (const vint4*)(dst + e0);
    const vint4* src4 = (const vint4*)(src + e0);

    auto scatter4 = [&](vint4 dv, vint4 sv) {
#pragma unroll
        for (int k = 0; k < 4; ++k) {
            int d = dv[k];
            int s = sv[k];
            if (d >= d0 && d < d1) {
                int pos = atomicAdd(&cnt[d], 1);
                if (pos < ELLC) {
                    ell[d * ELLC + pos] = (unsigned short)s;
                } else {  // P(deg>48) ~ 5e-11 per node
                    int j = atomicAdd(novf, 1);
                    if (j < OVF_CAP) { ovf_dst[j] = d; ovf_src[j] = s; }
                }
            }
        }
    };

    if (nq == (ECHUNK >> 2)) {   // full chunk: both loads up front, 8 chains
        vint4 dvA = __builtin_nontemporal_load(&dst4[t]);
        vint4 svA = __builtin_nontemporal_load(&src4[t]);
        vint4 dvB = __builtin_nontemporal_load(&dst4[t + 256]);
        vint4 svB = __builtin_nontemporal_load(&src4[t + 256]);
        scatter4(dvA, svA);
        scatter4(dvB, svB);
    } else {
        for (int qq = t; qq < nq; qq += 256) {
            vint4 dv = __builtin_nontemporal_load(&dst4[qq]);
            vint4 sv = __builtin_nontemporal_load(&src4[qq]);
            scatter4(dv, sv);
        }
        for (int e = e0 + (nq << 2) + t; e < e1; e += 256) {  // E % 4 tail
            int d = dst[e];
            if (d >= d0 && d < d1) {
                int pos = atomicAdd(&cnt[d], 1);
                int s   = src[e];
                if (pos < ELLC) {
                    ell[d * ELLC + pos] = (unsigned short)s;
                } else {
                    int j = atomicAdd(novf, 1);
                    if (j < OVF_CAP) { ovf_dst[j] = d; ovf_src[j] = s; }
                }
            }
        }
    }
}

// ---------------- per-dst GATv2 aggregation (grid-stride waves) -----------
// wave = 4 groups x 16 lanes; ELL row preloaded once, indices via __shfl.
__global__ __launch_bounds__(256) void gat_aggregate_kernel(
    const _Float16* __restrict__ xl, const float* __restrict__ xr,
    const int* __restrict__ cnt, const unsigned short* __restrict__ ell,
    const int* __restrict__ novf, const int* __restrict__ ovf_dst,
    const int* __restrict__ ovf_src,
    const float* __restrict__ att, const float* __restrict__ bias,
    float* __restrict__ out, int n) {
    int wid0 = (blockIdx.x * blockDim.x + threadIdx.x) >> 6;
    int nw   = (gridDim.x * blockDim.x) >> 6;
    int lane = threadIdx.x & 63;
    int g = lane >> 4;   // slot group
    int l = lane & 15;   // feature quad
    float4 att4 = ((const float4*)att)[l];
    float4 b4   = ((const float4*)bias)[l];

    for (int d = wid0; d < n; d += nw) {
        int deg_d = cnt[d];
        int nd  = min(deg_d, ELLC);
        int beg = d * ELLC;

        if (deg_d == 0) {   // isolated node: out = relu(bias)
            if (g == 0) {
                float4 v;
                v.x = fmaxf(b4.x, 0.f); v.y = fmaxf(b4.y, 0.f);
                v.z = fmaxf(b4.z, 0.f); v.w = fmaxf(b4.w, 0.f);
                ((float4*)(out + (size_t)d * 64))[l] = v;
            }
            continue;
        }

        // one coalesced 96B read of the whole ELL row; lane i holds slot i
        int myidx = 0;
        if (lane < ELLC) myidx = (int)ell[beg + lane];
        int i_first = __shfl(myidx, 0);

        float4 xr4 = ((const float4*)(xr + (size_t)d * 64))[l];
        float  s   = 0.f;
        float4 acc = make_float4(0.f, 0.f, 0.f, 0.f);

#pragma unroll 6
        for (int k = 0; k * 8 < nd; ++k) {     // k < 6; wave-uniform guard
            int  sa = k * 8 + g, sb = sa + 4;
            bool aa = sa < nd,   ab = sb < nd;
            int  i0 = __shfl(myidx, sa); if (!aa) i0 = i_first;
            int  i1 = __shfl(myidx, sb); if (!ab) i1 = i_first;
            half4 h0 = ((const half4*)(xl + (size_t)i0 * 64))[l];  // 8B gather
            half4 h1 = ((const half4*)(xl + (size_t)i1 * 64))[l];
            float4 x0 = make_float4((float)h0[0], (float)h0[1], (float)h0[2], (float)h0[3]);
            float4 x1 = make_float4((float)h1[0], (float)h1[1], (float)h1[2], (float)h1[3]);
            float z, c0 = 0.f, c1 = 0.f;
            z = x0.x + xr4.x; c0 += ((z > 0.f) ? z : 0.2f * z) * att4.x;
            z = x0.y + xr4.y; c0 += ((z > 0.f) ? z : 0.2f * z) * att4.y;
            z = x0.z + xr4.z; c0 += ((z > 0.f) ? z : 0.2f * z) * att4.z;
            z = x0.w + xr4.w; c0 += ((z > 0.f) ? z : 0.2f * z) * att4.w;
            z = x1.x + xr4.x; c1 += ((z > 0.f) ? z : 0.2f * z) * att4.x;
            z = x1.y + xr4.y; c1 += ((z > 0.f) ? z : 0.2f * z) * att4.y;
            z = x1.z + xr4.z; c1 += ((z > 0.f) ? z : 0.2f * z) * att4.z;
            z = x1.w + xr4.w; c1 += ((z > 0.f) ? z : 0.2f * z) * att4.w;
#pragma unroll
            for (int sh = 8; sh >= 1; sh >>= 1) {  // 16-lane reduce
                c0 += __shfl_xor(c0, sh);
                c1 += __shfl_xor(c1, sh);
            }
            float w0 = aa ? __expf(fminf(c0, 30.f)) : 0.f;
            float w1 = ab ? __expf(fminf(c1, 30.f)) : 0.f;
            s += w0 + w1;
            acc.x += w0 * x0.x + w1 * x1.x;
            acc.y += w0 * x0.y + w1 * x1.y;
            acc.z += w0 * x0.z + w1 * x1.z;
            acc.w += w0 * x0.w + w1 * x1.w;
        }
        // overflow fold (deg > ELLC): empty in practice
        if (deg_d > ELLC) {
            int no = min(*novf, OVF_CAP);
            for (int j = g; j < no; j += 4) {
                bool active = (ovf_dst[j] == d);
                int  i0     = active ? ovf_src[j] : i_first;
                half4 h0 = ((const half4*)(xl + (size_t)i0 * 64))[l];
                float4 x0 = make_float4((float)h0[0], (float)h0[1], (float)h0[2], (float)h0[3]);
                float z, c0 = 0.f;
                z = x0.x + xr4.x; c0 += ((z > 0.f) ? z : 0.2f * z) * att4.x;
                z = x0.y + xr4.y; c0 += ((z > 0.f) ? z : 0.2f * z) * att4.y;
                z = x0.z + xr4.z; c0 += ((z > 0.f) ? z : 0.2f * z) * att4.z;
                z = x0.w + xr4.w; c0 += ((z > 0.f) ? z : 0.2f * z) * att4.w;
#pragma unroll
                for (int sh = 8; sh >= 1; sh >>= 1) c0 += __shfl_xor(c0, sh);
                float w0 = active ? __expf(fminf(c0, 30.f)) : 0.f;
                s += w0;
                acc.x += w0 * x0.x;
                acc.y += w0 * x0.y;
                acc.z += w0 * x0.z;
                acc.w += w0 * x0.w;
            }
        }
        // merge the 4 group partial sums, xor 16 then xor 32
#pragma unroll
        for (int mask = 16; mask <= 32; mask <<= 1) {
            s     += __shfl_xor(s, mask);
            acc.x += __shfl_xor(acc.x, mask);
            acc.y += __shfl_xor(acc.y, mask);
            acc.z += __shfl_xor(acc.z, mask);
            acc.w += __shfl_xor(acc.w, mask);
        }
        if (g == 0) {
            float inv = (s > 0.f) ? (1.f / s) : 0.f;
            float4 v;
            v.x = fmaxf(acc.x * inv + b4.x, 0.f);
            v.y = fmaxf(acc.y * inv + b4.y, 0.f);
            v.z = fmaxf(acc.z * inv + b4.z, 0.f);
            v.w = fmaxf(acc.w * inv + b4.w, 0.f);
            ((float4*)(out + (size_t)d * 64))[l] = v;
        }
    }
}

// ---------------- mean pool + fused final (last-block ticket) -------------
__global__ __launch_bounds__(256) void pool_final_kernel(
    const float* __restrict__ h, const int* __restrict__ batch,
    float* __restrict__ sums, float* __restrict__ cnts, int n, int nwaves,
    int* __restrict__ done,
    const float* __restrict__ lin_w, const float* __restrict__ lin_b,
    float* __restrict__ out, int G) {
    __shared__ int ticketS;
    {
        int wid  = (blockIdx.x * blockDim.x + threadIdx.x) >> 6;
        int lane = threadIdx.x & 63;
        int per   = (n + nwaves - 1) / nwaves;
        int start = wid * per;
        int end   = min(n, start + per);
        if (start < end) {
            int cur   = batch[start];
            float acc = 0.f, cnt = 0.f;
            for (int i = start; i < end; ++i) {
                int g = batch[i];   // wave-uniform
                if (g != cur) {
                    atomicAdd(&sums[cur * 64 + lane], acc);
                    if (lane == 0) atomicAdd(&cnts[cur], cnt);
                    acc = 0.f; cnt = 0.f; cur = g;
                }
                acc += h[(size_t)i * 64 + lane];
                cnt += 1.f;
            }
            atomicAdd(&sums[cur * 64 + lane], acc);
            if (lane == 0) atomicAdd(&cnts[cur], cnt);
        }
    }
    __threadfence();           // publish this block's atomics (device scope)
    __syncthreads();
    if (threadIdx.x == 0) ticketS = atomicAdd(done, 1);
    __syncthreads();
    if (ticketS != (int)gridDim.x - 1) return;
    __threadfence();           // acquire all blocks' sums/cnts
    // last block computes the final linear: out[g,o]
    for (int i = threadIdx.x; i < G * 32; i += 256) {
        int g = i >> 5, o = i & 31;
        float inv = 1.f / fmaxf(cnts[g], 1.f);
        float a = 0.f;
#pragma unroll 8
        for (int hh = 0; hh < 64; ++hh) a += sums[g * 64 + hh] * lin_w[hh * 32 + o];
        out[i] = a * inv + lin_b[o];
    }
}

extern "C" void kernel_launch(void* const* d_in, const int* in_sizes, int n_in,
                              void* d_out, int out_size, void* d_ws, size_t ws_size,
                              hipStream_t stream) {
    const float* x     = (const float*)d_in[0];
    const int*   ei    = (const int*)d_in[1];
    const int*   batch = (const int*)d_in[2];
    const float* Wl1   = (const float*)d_in[3];
    const float* bl1   = (const float*)d_in[4];
    const float* Wr1   = (const float*)d_in[5];
    const float* br1   = (const float*)d_in[6];
    const float* att1  = (const float*)d_in[7];
    const float* bias1 = (const float*)d_in[8];
    const float* Wl2   = (const float*)d_in[9];
    const float* bl2   = (const float*)d_in[10];
    const float* Wr2   = (const float*)d_in[11];
    const float* br2   = (const float*)d_in[12];
    const float* att2  = (const float*)d_in[13];
    const float* bias2 = (const float*)d_in[14];
    const float* lin_w = (const float*)d_in[15];
    const float* lin_b = (const float*)d_in[16];
    float* out = (float*)d_out;

    const int N = in_sizes[0] / 64;
    const int E = in_sizes[1] / 2;
    const int G = out_size / 32;
    const int* src = ei;
    const int* dst = ei + E;

    // ---- workspace carve-up (256B-aligned) ----
    char*  ws  = (char*)d_ws;
    size_t off = 0;
    auto alloc = [&](size_t bytes) -> void* {
        void* p = ws + off;
        off += bytes;
        off = (off + 255) & ~(size_t)255;
        return p;
    };
    _Float16* xl   = (_Float16*)alloc((size_t)N * 64 * sizeof(_Float16));
    float* xr      = (float*)alloc((size_t)N * 64 * sizeof(float));
    float* h1      = (float*)alloc((size_t)N * 64 * sizeof(float));  // also h2
    // zeroed region (contiguous): cnt, novf+done, sums, cnts
    int*   cnt     = (int*)alloc((size_t)N * sizeof(int));
    int*   novf    = (int*)alloc(256);           // novf[0]=ovf count, novf[1]=done
    float* sums    = (float*)alloc((size_t)G * 64 * sizeof(float));
    float* cnts    = (float*)alloc((size_t)G * sizeof(float));
    char*  zend    = ws + off;
    unsigned short* ell = (unsigned short*)alloc((size_t)N * ELLC * sizeof(unsigned short));
    int*   ovf_dst = (int*)alloc((size_t)OVF_CAP * sizeof(int));
    int*   ovf_src = (int*)alloc((size_t)OVF_CAP * sizeof(int));

    (void)hipMemsetAsync(cnt, 0, (size_t)(zend - (char*)cnt), stream);

    int ggrid  = (N + GROWS - 1) / GROWS;
    int nchunk = (E + ECHUNK - 1) / ECHUNK;
    int fb     = nchunk * 8;                     // fill virtual blocks (x8 XCD)
    int psize  = (N + 7) / 8;                    // dst partition size
    // interleaved grid: groups of 24 = 16 fill + 8 gemm
    int ngroups = max((fb + 15) / 16, (ggrid + 7) / 8);
    int igrid   = ngroups * 24;
    int agrid   = 2048;                          // grid-stride agg (8192 waves)

    // ---- interleaved: XCD-partitioned ELL fill + layer-1 dual GEMM ----
    fill_gemm_kernel<<<igrid, 256, 0, stream>>>(
        src, dst, cnt, ell, novf, ovf_dst, ovf_src, E, N, psize, fb, ggrid,
        x, Wl1, bl1, Wr1, br1, xl, xr);

    gat_aggregate_kernel<<<agrid, 256, 0, stream>>>(
        xl, xr, cnt, ell, novf, ovf_dst, ovf_src, att1, bias1, h1, N);

    // ---- layer 2 (gemm2 reads h1, overwrites xl/xr; agg2 rewrites h1) ----
    dual_gemm64_kernel<<<ggrid, 256, 0, stream>>>(h1, Wl2, bl2, Wr2, br2, xl, xr, N);
    gat_aggregate_kernel<<<agrid, 256, 0, stream>>>(
        xl, xr, cnt, ell, novf, ovf_dst, ovf_src, att2, bias2, h1, N);

    // ---- pool + final linear (fused, last-block ticket) ----
    const int NWAVES = 2048;
    pool_final_kernel<<<512, 256, 0, stream>>>(h1, batch, sums, cnts, N, NWAVES,
                                               novf + 1, lin_w, lin_b, out, G);
}

// Round 15
// 271.252 us; speedup vs baseline: 1.4042x; 1.4042x over previous
//
#include <hip/hip_runtime.h>
#include <hip/hip_fp16.h>
#include <math.h>

// ---------------------------------------------------------------------------
// GATv2 x2 + mean-pool + linear, MI355X.
// R15: revert R14's pool+final last-block fusion (it ran the final linear on
//      ONE CU: 130us, 6.6% occ). Separate pool (512 blk) + final (64 blk).
//      Keep interleaved fill/gemm1 and grid-stride aggregate (neutral).
//      Best so far: R13 = 252us.
// ---------------------------------------------------------------------------

#define ELLC    48
#define OVF_CAP 65536
#define ECHUNK  2048          // edges per fill virtual block

typedef int      vint4 __attribute__((ext_vector_type(4)));
typedef _Float16 half4 __attribute__((ext_vector_type(4)));

// ---------------- slim dual GEMM body: xl = X*Wl + bl (fp16), xr = X*Wr + br
#define GROWS 32
__device__ __forceinline__ void dual_gemm_slim(
    int bid, int t,
    const float* __restrict__ X,
    const float* __restrict__ Wl, const float* __restrict__ bl,
    const float* __restrict__ Wr, const float* __restrict__ br,
    _Float16* __restrict__ xl, float* __restrict__ xr, int n,
    float* xS) {
    int row0 = bid * GROWS;
    for (int i = t; i < GROWS * 16; i += 256) {
        int r = row0 + (i >> 4);
        float4 v = make_float4(0.f, 0.f, 0.f, 0.f);
        if (r < n) v = ((const float4*)(X + (size_t)r * 64))[i & 15];
        ((float4*)xS)[i] = v;
    }
    __syncthreads();
    int h  = t & 63;
    int rb = t >> 6;  // 0..3
    float accl[8], accr[8];
#pragma unroll
    for (int i = 0; i < 8; ++i) { accl[i] = 0.f; accr[i] = 0.f; }
#pragma unroll 4
    for (int d = 0; d < 64; ++d) {
        float wl = Wl[d * 64 + h];   // coalesced 256B, L2-hot
        float wr = Wr[d * 64 + h];
#pragma unroll
        for (int i = 0; i < 8; ++i) {
            float xv = xS[(rb + 4 * i) * 64 + d];  // wave-uniform broadcast
            accl[i] += xv * wl;
            accr[i] += xv * wr;
        }
    }
    float blv = bl[h], brv = br[h];
#pragma unroll
    for (int i = 0; i < 8; ++i) {
        int r = row0 + rb + 4 * i;
        if (r < n) {
            xl[(size_t)r * 64 + h] = (_Float16)(accl[i] + blv);  // 2B, coalesced
            xr[(size_t)r * 64 + h] = accr[i] + brv;
        }
    }
}

__global__ __launch_bounds__(256) void dual_gemm64_kernel(
    const float* __restrict__ X,
    const float* __restrict__ Wl, const float* __restrict__ bl,
    const float* __restrict__ Wr, const float* __restrict__ br,
    _Float16* __restrict__ xl, float* __restrict__ xr, int n) {
    __shared__ float xS[GROWS * 64];
    dual_gemm_slim(blockIdx.x, threadIdx.x, X, Wl, bl, Wr, br, xl, xr, n, xS);
}

// ---------------- interleaved: XCD-partitioned ELL fill + layer-1 GEMM ----
// 24-block groups: r = b%24. r<16 -> fill vb = (b/24)*16+r (vb&7 == b&7!);
// r>=16 -> gemm vg = (b/24)*8 + (r-16).
__global__ __launch_bounds__(256) void fill_gemm_kernel(
    const int* __restrict__ src, const int* __restrict__ dst,
    int* __restrict__ cnt, unsigned short* __restrict__ ell,
    int* __restrict__ novf, int* __restrict__ ovf_dst, int* __restrict__ ovf_src,
    int E, int N, int psize, int fb, int ggrid,
    const float* __restrict__ X,
    const float* __restrict__ Wl, const float* __restrict__ bl,
    const float* __restrict__ Wr, const float* __restrict__ br,
    _Float16* __restrict__ xl, float* __restrict__ xr) {
    __shared__ float xS[GROWS * 64];
    int b = blockIdx.x;
    int q = b / 24, r = b % 24;
    if (r >= 16) {
        int vg = q * 8 + (r - 16);
        if (vg < ggrid)
            dual_gemm_slim(vg, threadIdx.x, X, Wl, bl, Wr, br, xl, xr, N, xS);
        return;
    }
    int vb = q * 16 + r;
    if (vb >= fb) return;
    int t     = threadIdx.x;
    int chunk = vb >> 3;
    int p     = vb & 7;                   // partition == XCD (== b&7)
    int d0    = p * psize;
    int d1    = min(N, d0 + psize);
    int e0    = chunk * ECHUNK;
    int e1    = min(E, e0 + ECHUNK);
    int nq    = (e1 - e0) >> 2;
    const vint4* dst4 = (const vint4*)(dst + e0);
    const vint4* src4 = (const vint4*)(src + e0);

    auto scatter4 = [&](vint4 dv, vint4 sv) {
#pragma unroll
        for (int k = 0; k < 4; ++k) {
            int d = dv[k];
            int s = sv[k];
            if (d >= d0 && d < d1) {
                int pos = atomicAdd(&cnt[d], 1);
                if (pos < ELLC) {
                    ell[d * ELLC + pos] = (unsigned short)s;
                } else {  // P(deg>48) ~ 5e-11 per node
                    int j = atomicAdd(novf, 1);
                    if (j < OVF_CAP) { ovf_dst[j] = d; ovf_src[j] = s; }
                }
            }
        }
    };

    if (nq == (ECHUNK >> 2)) {   // full chunk: both loads up front, 8 chains
        vint4 dvA = __builtin_nontemporal_load(&dst4[t]);
        vint4 svA = __builtin_nontemporal_load(&src4[t]);
        vint4 dvB = __builtin_nontemporal_load(&dst4[t + 256]);
        vint4 svB = __builtin_nontemporal_load(&src4[t + 256]);
        scatter4(dvA, svA);
        scatter4(dvB, svB);
    } else {
        for (int qq = t; qq < nq; qq += 256) {
            vint4 dv = __builtin_nontemporal_load(&dst4[qq]);
            vint4 sv = __builtin_nontemporal_load(&src4[qq]);
            scatter4(dv, sv);
        }
        for (int e = e0 + (nq << 2) + t; e < e1; e += 256) {  // E % 4 tail
            int d = dst[e];
            if (d >= d0 && d < d1) {
                int pos = atomicAdd(&cnt[d], 1);
                int s   = src[e];
                if (pos < ELLC) {
                    ell[d * ELLC + pos] = (unsigned short)s;
                } else {
                    int j = atomicAdd(novf, 1);
                    if (j < OVF_CAP) { ovf_dst[j] = d; ovf_src[j] = s; }
                }
            }
        }
    }
}

// ---------------- per-dst GATv2 aggregation (grid-stride waves) -----------
// wave = 4 groups x 16 lanes; ELL row preloaded once, indices via __shfl.
__global__ __launch_bounds__(256) void gat_aggregate_kernel(
    const _Float16* __restrict__ xl, const float* __restrict__ xr,
    const int* __restrict__ cnt, const unsigned short* __restrict__ ell,
    const int* __restrict__ novf, const int* __restrict__ ovf_dst,
    const int* __restrict__ ovf_src,
    const float* __restrict__ att, const float* __restrict__ bias,
    float* __restrict__ out, int n) {
    int wid0 = (blockIdx.x * blockDim.x + threadIdx.x) >> 6;
    int nw   = (gridDim.x * blockDim.x) >> 6;
    int lane = threadIdx.x & 63;
    int g = lane >> 4;   // slot group
    int l = lane & 15;   // feature quad
    float4 att4 = ((const float4*)att)[l];
    float4 b4   = ((const float4*)bias)[l];

    for (int d = wid0; d < n; d += nw) {
        int deg_d = cnt[d];
        int nd  = min(deg_d, ELLC);
        int beg = d * ELLC;

        if (deg_d == 0) {   // isolated node: out = relu(bias)
            if (g == 0) {
                float4 v;
                v.x = fmaxf(b4.x, 0.f); v.y = fmaxf(b4.y, 0.f);
                v.z = fmaxf(b4.z, 0.f); v.w = fmaxf(b4.w, 0.f);
                ((float4*)(out + (size_t)d * 64))[l] = v;
            }
            continue;
        }

        // one coalesced 96B read of the whole ELL row; lane i holds slot i
        int myidx = 0;
        if (lane < ELLC) myidx = (int)ell[beg + lane];
        int i_first = __shfl(myidx, 0);

        float4 xr4 = ((const float4*)(xr + (size_t)d * 64))[l];
        float  s   = 0.f;
        float4 acc = make_float4(0.f, 0.f, 0.f, 0.f);

#pragma unroll 6
        for (int k = 0; k * 8 < nd; ++k) {     // k < 6; wave-uniform guard
            int  sa = k * 8 + g, sb = sa + 4;
            bool aa = sa < nd,   ab = sb < nd;
            int  i0 = __shfl(myidx, sa); if (!aa) i0 = i_first;
            int  i1 = __shfl(myidx, sb); if (!ab) i1 = i_first;
            half4 h0 = ((const half4*)(xl + (size_t)i0 * 64))[l];  // 8B gather
            half4 h1 = ((const half4*)(xl + (size_t)i1 * 64))[l];
            float4 x0 = make_float4((float)h0[0], (float)h0[1], (float)h0[2], (float)h0[3]);
            float4 x1 = make_float4((float)h1[0], (float)h1[1], (float)h1[2], (float)h1[3]);
            float z, c0 = 0.f, c1 = 0.f;
            z = x0.x + xr4.x; c0 += ((z > 0.f) ? z : 0.2f * z) * att4.x;
            z = x0.y + xr4.y; c0 += ((z > 0.f) ? z : 0.2f * z) * att4.y;
            z = x0.z + xr4.z; c0 += ((z > 0.f) ? z : 0.2f * z) * att4.z;
            z = x0.w + xr4.w; c0 += ((z > 0.f) ? z : 0.2f * z) * att4.w;
            z = x1.x + xr4.x; c1 += ((z > 0.f) ? z : 0.2f * z) * att4.x;
            z = x1.y + xr4.y; c1 += ((z > 0.f) ? z : 0.2f * z) * att4.y;
            z = x1.z + xr4.z; c1 += ((z > 0.f) ? z : 0.2f * z) * att4.z;
            z = x1.w + xr4.w; c1 += ((z > 0.f) ? z : 0.2f * z) * att4.w;
#pragma unroll
            for (int sh = 8; sh >= 1; sh >>= 1) {  // 16-lane reduce
                c0 += __shfl_xor(c0, sh);
                c1 += __shfl_xor(c1, sh);
            }
            float w0 = aa ? __expf(fminf(c0, 30.f)) : 0.f;
            float w1 = ab ? __expf(fminf(c1, 30.f)) : 0.f;
            s += w0 + w1;
            acc.x += w0 * x0.x + w1 * x1.x;
            acc.y += w0 * x0.y + w1 * x1.y;
            acc.z += w0 * x0.z + w1 * x1.z;
            acc.w += w0 * x0.w + w1 * x1.w;
        }
        // overflow fold (deg > ELLC): empty in practice
        if (deg_d > ELLC) {
            int no = min(*novf, OVF_CAP);
            for (int j = g; j < no; j += 4) {
                bool active = (ovf_dst[j] == d);
                int  i0     = active ? ovf_src[j] : i_first;
                half4 h0 = ((const half4*)(xl + (size_t)i0 * 64))[l];
                float4 x0 = make_float4((float)h0[0], (float)h0[1], (float)h0[2], (float)h0[3]);
                float z, c0 = 0.f;
                z = x0.x + xr4.x; c0 += ((z > 0.f) ? z : 0.2f * z) * att4.x;
                z = x0.y + xr4.y; c0 += ((z > 0.f) ? z : 0.2f * z) * att4.y;
                z = x0.z + xr4.z; c0 += ((z > 0.f) ? z : 0.2f * z) * att4.z;
                z = x0.w + xr4.w; c0 += ((z > 0.f) ? z : 0.2f * z) * att4.w;
#pragma unroll
                for (int sh = 8; sh >= 1; sh >>= 1) c0 += __shfl_xor(c0, sh);
                float w0 = active ? __expf(fminf(c0, 30.f)) : 0.f;
                s += w0;
                acc.x += w0 * x0.x;
                acc.y += w0 * x0.y;
                acc.z += w0 * x0.z;
                acc.w += w0 * x0.w;
            }
        }
        // merge the 4 group partial sums, xor 16 then xor 32
#pragma unroll
        for (int mask = 16; mask <= 32; mask <<= 1) {
            s     += __shfl_xor(s, mask);
            acc.x += __shfl_xor(acc.x, mask);
            acc.y += __shfl_xor(acc.y, mask);
            acc.z += __shfl_xor(acc.z, mask);
            acc.w += __shfl_xor(acc.w, mask);
        }
        if (g == 0) {
            float inv = (s > 0.f) ? (1.f / s) : 0.f;
            float4 v;
            v.x = fmaxf(acc.x * inv + b4.x, 0.f);
            v.y = fmaxf(acc.y * inv + b4.y, 0.f);
            v.z = fmaxf(acc.z * inv + b4.z, 0.f);
            v.w = fmaxf(acc.w * inv + b4.w, 0.f);
            ((float4*)(out + (size_t)d * 64))[l] = v;
        }
    }
}

// ---------------- mean pool over sorted batch ----------------
__global__ __launch_bounds__(256) void pool_kernel(
    const float* __restrict__ h, const int* __restrict__ batch,
    float* __restrict__ sums, float* __restrict__ cnts, int n, int nwaves) {
    int wid  = (blockIdx.x * blockDim.x + threadIdx.x) >> 6;
    int lane = threadIdx.x & 63;
    int per   = (n + nwaves - 1) / nwaves;
    int start = wid * per;
    int end   = min(n, start + per);
    if (start >= end) return;
    int cur   = batch[start];
    float acc = 0.f, cnt = 0.f;
    for (int i = start; i < end; ++i) {
        int g = batch[i];   // wave-uniform
        if (g != cur) {
            atomicAdd(&sums[cur * 64 + lane], acc);
            if (lane == 0) atomicAdd(&cnts[cur], cnt);
            acc = 0.f; cnt = 0.f; cur = g;
        }
        acc += h[(size_t)i * 64 + lane];
        cnt += 1.f;
    }
    atomicAdd(&sums[cur * 64 + lane], acc);
    if (lane == 0) atomicAdd(&cnts[cur], cnt);
}

// ---------------- final: out = (sums/cnt) @ lin_w + lin_b ----------------
__global__ __launch_bounds__(256) void final_kernel(
    const float* __restrict__ sums, const float* __restrict__ cnts,
    const float* __restrict__ lin_w, const float* __restrict__ lin_b,
    float* __restrict__ out, int total) {
    int tid = blockIdx.x * blockDim.x + threadIdx.x;
    if (tid >= total) return;
    int g = tid >> 5, o = tid & 31;
    float inv = 1.f / fmaxf(cnts[g], 1.f);
    float a = 0.f;
    for (int h = 0; h < 64; ++h) a += sums[g * 64 + h] * lin_w[h * 32 + o];
    out[tid] = a * inv + lin_b[o];
}

extern "C" void kernel_launch(void* const* d_in, const int* in_sizes, int n_in,
                              void* d_out, int out_size, void* d_ws, size_t ws_size,
                              hipStream_t stream) {
    const float* x     = (const float*)d_in[0];
    const int*   ei    = (const int*)d_in[1];
    const int*   batch = (const int*)d_in[2];
    const float* Wl1   = (const float*)d_in[3];
    const float* bl1   = (const float*)d_in[4];
    const float* Wr1   = (const float*)d_in[5];
    const float* br1   = (const float*)d_in[6];
    const float* att1  = (const float*)d_in[7];
    const float* bias1 = (const float*)d_in[8];
    const float* Wl2   = (const float*)d_in[9];
    const float* bl2   = (const float*)d_in[10];
    const float* Wr2   = (const float*)d_in[11];
    const float* br2   = (const float*)d_in[12];
    const float* att2  = (const float*)d_in[13];
    const float* bias2 = (const float*)d_in[14];
    const float* lin_w = (const float*)d_in[15];
    const float* lin_b = (const float*)d_in[16];
    float* out = (float*)d_out;

    const int N = in_sizes[0] / 64;
    const int E = in_sizes[1] / 2;
    const int G = out_size / 32;
    const int* src = ei;
    const int* dst = ei + E;

    // ---- workspace carve-up (256B-aligned) ----
    char*  ws  = (char*)d_ws;
    size_t off = 0;
    auto alloc = [&](size_t bytes) -> void* {
        void* p = ws + off;
        off += bytes;
        off = (off + 255) & ~(size_t)255;
        return p;
    };
    _Float16* xl   = (_Float16*)alloc((size_t)N * 64 * sizeof(_Float16));
    float* xr      = (float*)alloc((size_t)N * 64 * sizeof(float));
    float* h1      = (float*)alloc((size_t)N * 64 * sizeof(float));  // also h2
    // zeroed region (contiguous): cnt, novf, sums, cnts
    int*   cnt     = (int*)alloc((size_t)N * sizeof(int));
    int*   novf    = (int*)alloc(256);
    float* sums    = (float*)alloc((size_t)G * 64 * sizeof(float));
    float* cnts    = (float*)alloc((size_t)G * sizeof(float));
    char*  zend    = ws + off;
    unsigned short* ell = (unsigned short*)alloc((size_t)N * ELLC * sizeof(unsigned short));
    int*   ovf_dst = (int*)alloc((size_t)OVF_CAP * sizeof(int));
    int*   ovf_src = (int*)alloc((size_t)OVF_CAP * sizeof(int));

    (void)hipMemsetAsync(cnt, 0, (size_t)(zend - (char*)cnt), stream);

    int ggrid  = (N + GROWS - 1) / GROWS;
    int nchunk = (E + ECHUNK - 1) / ECHUNK;
    int fb     = nchunk * 8;                     // fill virtual blocks (x8 XCD)
    int psize  = (N + 7) / 8;                    // dst partition size
    // interleaved grid: groups of 24 = 16 fill + 8 gemm
    int ngroups = max((fb + 15) / 16, (ggrid + 7) / 8);
    int igrid   = ngroups * 24;
    int agrid   = 2048;                          // grid-stride agg (8192 waves)

    // ---- interleaved: XCD-partitioned ELL fill + layer-1 dual GEMM ----
    fill_gemm_kernel<<<igrid, 256, 0, stream>>>(
        src, dst, cnt, ell, novf, ovf_dst, ovf_src, E, N, psize, fb, ggrid,
        x, Wl1, bl1, Wr1, br1, xl, xr);

    gat_aggregate_kernel<<<agrid, 256, 0, stream>>>(
        xl, xr, cnt, ell, novf, ovf_dst, ovf_src, att1, bias1, h1, N);

    // ---- layer 2 (gemm2 reads h1, overwrites xl/xr; agg2 rewrites h1) ----
    dual_gemm64_kernel<<<ggrid, 256, 0, stream>>>(h1, Wl2, bl2, Wr2, br2, xl, xr, N);
    gat_aggregate_kernel<<<agrid, 256, 0, stream>>>(
        xl, xr, cnt, ell, novf, ovf_dst, ovf_src, att2, bias2, h1, N);

    // ---- pool + final linear (separate dispatches; R14 fusion was 130us) ----
    const int NWAVES = 2048;
    pool_kernel<<<512, 256, 0, stream>>>(h1, batch, sums, cnts, N, NWAVES);
    int total = G * 32;
    final_kernel<<<(total + 255) / 256, 256, 0, stream>>>(sums, cnts, lin_w, lin_b, out, total);
}

// Round 16
// 246.417 us; speedup vs baseline: 1.5457x; 1.1008x over previous
//
#include <hip/hip_runtime.h>
#include <hip/hip_fp16.h>
#include <math.h>

// ---------------------------------------------------------------------------
// GATv2 x2 + mean-pool + linear, MI355X.
// R16: best-of-both. R15's interleaved fill/gemm1 (61->52us: fill atomic
//      stalls co-scheduled with gemm VALU) + R13's per-node aggregate
//      (one wave per dst; R15's grid-stride wave = sum of ~6 random degrees
//      -> intra-wave load imbalance, +15us/dispatch. One node per wave lets
//      the scheduler smooth degree variance).
// ---------------------------------------------------------------------------

#define ELLC    48
#define OVF_CAP 65536
#define ECHUNK  2048          // edges per fill virtual block

typedef int      vint4 __attribute__((ext_vector_type(4)));
typedef _Float16 half4 __attribute__((ext_vector_type(4)));

// ---------------- slim dual GEMM body: xl = X*Wl + bl (fp16), xr = X*Wr + br
#define GROWS 32
__device__ __forceinline__ void dual_gemm_slim(
    int bid, int t,
    const float* __restrict__ X,
    const float* __restrict__ Wl, const float* __restrict__ bl,
    const float* __restrict__ Wr, const float* __restrict__ br,
    _Float16* __restrict__ xl, float* __restrict__ xr, int n,
    float* xS) {
    int row0 = bid * GROWS;
    for (int i = t; i < GROWS * 16; i += 256) {
        int r = row0 + (i >> 4);
        float4 v = make_float4(0.f, 0.f, 0.f, 0.f);
        if (r < n) v = ((const float4*)(X + (size_t)r * 64))[i & 15];
        ((float4*)xS)[i] = v;
    }
    __syncthreads();
    int h  = t & 63;
    int rb = t >> 6;  // 0..3
    float accl[8], accr[8];
#pragma unroll
    for (int i = 0; i < 8; ++i) { accl[i] = 0.f; accr[i] = 0.f; }
#pragma unroll 4
    for (int d = 0; d < 64; ++d) {
        float wl = Wl[d * 64 + h];   // coalesced 256B, L2-hot
        float wr = Wr[d * 64 + h];
#pragma unroll
        for (int i = 0; i < 8; ++i) {
            float xv = xS[(rb + 4 * i) * 64 + d];  // wave-uniform broadcast
            accl[i] += xv * wl;
            accr[i] += xv * wr;
        }
    }
    float blv = bl[h], brv = br[h];
#pragma unroll
    for (int i = 0; i < 8; ++i) {
        int r = row0 + rb + 4 * i;
        if (r < n) {
            xl[(size_t)r * 64 + h] = (_Float16)(accl[i] + blv);  // 2B, coalesced
            xr[(size_t)r * 64 + h] = accr[i] + brv;
        }
    }
}

__global__ __launch_bounds__(256) void dual_gemm64_kernel(
    const float* __restrict__ X,
    const float* __restrict__ Wl, const float* __restrict__ bl,
    const float* __restrict__ Wr, const float* __restrict__ br,
    _Float16* __restrict__ xl, float* __restrict__ xr, int n) {
    __shared__ float xS[GROWS * 64];
    dual_gemm_slim(blockIdx.x, threadIdx.x, X, Wl, bl, Wr, br, xl, xr, n, xS);
}

// ---------------- interleaved: XCD-partitioned ELL fill + layer-1 GEMM ----
// 24-block groups: r = b%24. r<16 -> fill vb = (b/24)*16+r (vb&7 == b&7!);
// r>=16 -> gemm vg = (b/24)*8 + (r-16).
__global__ __launch_bounds__(256) void fill_gemm_kernel(
    const int* __restrict__ src, const int* __restrict__ dst,
    int* __restrict__ cnt, unsigned short* __restrict__ ell,
    int* __restrict__ novf, int* __restrict__ ovf_dst, int* __restrict__ ovf_src,
    int E, int N, int psize, int fb, int ggrid,
    const float* __restrict__ X,
    const float* __restrict__ Wl, const float* __restrict__ bl,
    const float* __restrict__ Wr, const float* __restrict__ br,
    _Float16* __restrict__ xl, float* __restrict__ xr) {
    __shared__ float xS[GROWS * 64];
    int b = blockIdx.x;
    int q = b / 24, r = b % 24;
    if (r >= 16) {
        int vg = q * 8 + (r - 16);
        if (vg < ggrid)
            dual_gemm_slim(vg, threadIdx.x, X, Wl, bl, Wr, br, xl, xr, N, xS);
        return;
    }
    int vb = q * 16 + r;
    if (vb >= fb) return;
    int t     = threadIdx.x;
    int chunk = vb >> 3;
    int p     = vb & 7;                   // partition == XCD (== b&7)
    int d0    = p * psize;
    int d1    = min(N, d0 + psize);
    int e0    = chunk * ECHUNK;
    int e1    = min(E, e0 + ECHUNK);
    int nq    = (e1 - e0) >> 2;
    const vint4* dst4 = (const vint4*)(dst + e0);
    const vint4* src4 = (const vint4*)(src + e0);

    auto scatter4 = [&](vint4 dv, vint4 sv) {
#pragma unroll
        for (int k = 0; k < 4; ++k) {
            int d = dv[k];
            int s = sv[k];
            if (d >= d0 && d < d1) {
                int pos = atomicAdd(&cnt[d], 1);
                if (pos < ELLC) {
                    ell[d * ELLC + pos] = (unsigned short)s;
                } else {  // P(deg>48) ~ 5e-11 per node
                    int j = atomicAdd(novf, 1);
                    if (j < OVF_CAP) { ovf_dst[j] = d; ovf_src[j] = s; }
                }
            }
        }
    };

    if (nq == (ECHUNK >> 2)) {   // full chunk: both loads up front, 8 chains
        vint4 dvA = __builtin_nontemporal_load(&dst4[t]);
        vint4 svA = __builtin_nontemporal_load(&src4[t]);
        vint4 dvB = __builtin_nontemporal_load(&dst4[t + 256]);
        vint4 svB = __builtin_nontemporal_load(&src4[t + 256]);
        scatter4(dvA, svA);
        scatter4(dvB, svB);
    } else {
        for (int qq = t; qq < nq; qq += 256) {
            vint4 dv = __builtin_nontemporal_load(&dst4[qq]);
            vint4 sv = __builtin_nontemporal_load(&src4[qq]);
            scatter4(dv, sv);
        }
        for (int e = e0 + (nq << 2) + t; e < e1; e += 256) {  // E % 4 tail
            int d = dst[e];
            if (d >= d0 && d < d1) {
                int pos = atomicAdd(&cnt[d], 1);
                int s   = src[e];
                if (pos < ELLC) {
                    ell[d * ELLC + pos] = (unsigned short)s;
                } else {
                    int j = atomicAdd(novf, 1);
                    if (j < OVF_CAP) { ovf_dst[j] = d; ovf_src[j] = s; }
                }
            }
        }
    }
}

// ---------------- per-dst GATv2 aggregation (one wave per dst) ------------
// wave = 4 groups x 16 lanes; ELL row preloaded once, indices via __shfl.
__global__ __launch_bounds__(256) void gat_aggregate_kernel(
    const _Float16* __restrict__ xl, const float* __restrict__ xr,
    const int* __restrict__ cnt, const unsigned short* __restrict__ ell,
    const int* __restrict__ novf, const int* __restrict__ ovf_dst,
    const int* __restrict__ ovf_src,
    const float* __restrict__ att, const float* __restrict__ bias,
    float* __restrict__ out, int n) {
    int wid  = (blockIdx.x * blockDim.x + threadIdx.x) >> 6;
    int lane = threadIdx.x & 63;
    if (wid >= n) return;
    int g = lane >> 4;   // slot group
    int l = lane & 15;   // feature quad
    int d = wid;

    float4 att4 = ((const float4*)att)[l];
    float4 b4   = ((const float4*)bias)[l];
    int deg_d = cnt[d];
    int nd  = min(deg_d, ELLC);
    int beg = d * ELLC;

    if (deg_d == 0) {   // isolated node: out = relu(bias)
        if (g == 0) {
            float4 v;
            v.x = fmaxf(b4.x, 0.f); v.y = fmaxf(b4.y, 0.f);
            v.z = fmaxf(b4.z, 0.f); v.w = fmaxf(b4.w, 0.f);
            ((float4*)(out + (size_t)d * 64))[l] = v;
        }
        return;
    }

    // one coalesced 96B read of the whole ELL row; lane i holds slot i
    int myidx = 0;
    if (lane < ELLC) myidx = (int)ell[beg + lane];
    int i_first = __shfl(myidx, 0);

    float4 xr4 = ((const float4*)(xr + (size_t)d * 64))[l];
    float  s   = 0.f;
    float4 acc = make_float4(0.f, 0.f, 0.f, 0.f);

#pragma unroll 6
    for (int k = 0; k * 8 < nd; ++k) {     // k < 6 (nd <= 48); wave-uniform
        int  sa = k * 8 + g, sb = sa + 4;
        bool aa = sa < nd,   ab = sb < nd;
        int  i0 = __shfl(myidx, sa); if (!aa) i0 = i_first;
        int  i1 = __shfl(myidx, sb); if (!ab) i1 = i_first;
        half4 h0 = ((const half4*)(xl + (size_t)i0 * 64))[l];  // 8B gather
        half4 h1 = ((const half4*)(xl + (size_t)i1 * 64))[l];
        float4 x0 = make_float4((float)h0[0], (float)h0[1], (float)h0[2], (float)h0[3]);
        float4 x1 = make_float4((float)h1[0], (float)h1[1], (float)h1[2], (float)h1[3]);
        float z, c0 = 0.f, c1 = 0.f;
        z = x0.x + xr4.x; c0 += ((z > 0.f) ? z : 0.2f * z) * att4.x;
        z = x0.y + xr4.y; c0 += ((z > 0.f) ? z : 0.2f * z) * att4.y;
        z = x0.z + xr4.z; c0 += ((z > 0.f) ? z : 0.2f * z) * att4.z;
        z = x0.w + xr4.w; c0 += ((z > 0.f) ? z : 0.2f * z) * att4.w;
        z = x1.x + xr4.x; c1 += ((z > 0.f) ? z : 0.2f * z) * att4.x;
        z = x1.y + xr4.y; c1 += ((z > 0.f) ? z : 0.2f * z) * att4.y;
        z = x1.z + xr4.z; c1 += ((z > 0.f) ? z : 0.2f * z) * att4.z;
        z = x1.w + xr4.w; c1 += ((z > 0.f) ? z : 0.2f * z) * att4.w;
#pragma unroll
        for (int sh = 8; sh >= 1; sh >>= 1) {  // 16-lane reduce
            c0 += __shfl_xor(c0, sh);
            c1 += __shfl_xor(c1, sh);
        }
        float w0 = aa ? __expf(fminf(c0, 30.f)) : 0.f;
        float w1 = ab ? __expf(fminf(c1, 30.f)) : 0.f;
        s += w0 + w1;
        acc.x += w0 * x0.x + w1 * x1.x;
        acc.y += w0 * x0.y + w1 * x1.y;
        acc.z += w0 * x0.z + w1 * x1.z;
        acc.w += w0 * x0.w + w1 * x1.w;
    }
    // overflow fold (deg > ELLC): scan tiny global list; empty in practice
    if (deg_d > ELLC) {
        int no = min(*novf, OVF_CAP);
        for (int j = g; j < no; j += 4) {
            bool active = (ovf_dst[j] == d);
            int  i0     = active ? ovf_src[j] : i_first;
            half4 h0 = ((const half4*)(xl + (size_t)i0 * 64))[l];
            float4 x0 = make_float4((float)h0[0], (float)h0[1], (float)h0[2], (float)h0[3]);
            float z, c0 = 0.f;
            z = x0.x + xr4.x; c0 += ((z > 0.f) ? z : 0.2f * z) * att4.x;
            z = x0.y + xr4.y; c0 += ((z > 0.f) ? z : 0.2f * z) * att4.y;
            z = x0.z + xr4.z; c0 += ((z > 0.f) ? z : 0.2f * z) * att4.z;
            z = x0.w + xr4.w; c0 += ((z > 0.f) ? z : 0.2f * z) * att4.w;
#pragma unroll
            for (int sh = 8; sh >= 1; sh >>= 1) c0 += __shfl_xor(c0, sh);
            float w0 = active ? __expf(fminf(c0, 30.f)) : 0.f;
            s += w0;
            acc.x += w0 * x0.x;
            acc.y += w0 * x0.y;
            acc.z += w0 * x0.z;
            acc.w += w0 * x0.w;
        }
    }
    // merge the 4 group partial sums (plain adds), xor 16 then xor 32
#pragma unroll
    for (int mask = 16; mask <= 32; mask <<= 1) {
        s     += __shfl_xor(s, mask);
        acc.x += __shfl_xor(acc.x, mask);
        acc.y += __shfl_xor(acc.y, mask);
        acc.z += __shfl_xor(acc.z, mask);
        acc.w += __shfl_xor(acc.w, mask);
    }
    if (g == 0) {
        float inv = (s > 0.f) ? (1.f / s) : 0.f;
        float4 v;
        v.x = fmaxf(acc.x * inv + b4.x, 0.f);
        v.y = fmaxf(acc.y * inv + b4.y, 0.f);
        v.z = fmaxf(acc.z * inv + b4.z, 0.f);
        v.w = fmaxf(acc.w * inv + b4.w, 0.f);
        ((float4*)(out + (size_t)d * 64))[l] = v;
    }
}

// ---------------- mean pool over sorted batch ----------------
__global__ __launch_bounds__(256) void pool_kernel(
    const float* __restrict__ h, const int* __restrict__ batch,
    float* __restrict__ sums, float* __restrict__ cnts, int n, int nwaves) {
    int wid  = (blockIdx.x * blockDim.x + threadIdx.x) >> 6;
    int lane = threadIdx.x & 63;
    int per   = (n + nwaves - 1) / nwaves;
    int start = wid * per;
    int end   = min(n, start + per);
    if (start >= end) return;
    int cur   = batch[start];
    float acc = 0.f, cnt = 0.f;
    for (int i = start; i < end; ++i) {
        int g = batch[i];   // wave-uniform
        if (g != cur) {
            atomicAdd(&sums[cur * 64 + lane], acc);
            if (lane == 0) atomicAdd(&cnts[cur], cnt);
            acc = 0.f; cnt = 0.f; cur = g;
        }
        acc += h[(size_t)i * 64 + lane];
        cnt += 1.f;
    }
    atomicAdd(&sums[cur * 64 + lane], acc);
    if (lane == 0) atomicAdd(&cnts[cur], cnt);
}

// ---------------- final: out = (sums/cnt) @ lin_w + lin_b ----------------
__global__ __launch_bounds__(256) void final_kernel(
    const float* __restrict__ sums, const float* __restrict__ cnts,
    const float* __restrict__ lin_w, const float* __restrict__ lin_b,
    float* __restrict__ out, int total) {
    int tid = blockIdx.x * blockDim.x + threadIdx.x;
    if (tid >= total) return;
    int g = tid >> 5, o = tid & 31;
    float inv = 1.f / fmaxf(cnts[g], 1.f);
    float a = 0.f;
    for (int h = 0; h < 64; ++h) a += sums[g * 64 + h] * lin_w[h * 32 + o];
    out[tid] = a * inv + lin_b[o];
}

extern "C" void kernel_launch(void* const* d_in, const int* in_sizes, int n_in,
                              void* d_out, int out_size, void* d_ws, size_t ws_size,
                              hipStream_t stream) {
    const float* x     = (const float*)d_in[0];
    const int*   ei    = (const int*)d_in[1];
    const int*   batch = (const int*)d_in[2];
    const float* Wl1   = (const float*)d_in[3];
    const float* bl1   = (const float*)d_in[4];
    const float* Wr1   = (const float*)d_in[5];
    const float* br1   = (const float*)d_in[6];
    const float* att1  = (const float*)d_in[7];
    const float* bias1 = (const float*)d_in[8];
    const float* Wl2   = (const float*)d_in[9];
    const float* bl2   = (const float*)d_in[10];
    const float* Wr2   = (const float*)d_in[11];
    const float* br2   = (const float*)d_in[12];
    const float* att2  = (const float*)d_in[13];
    const float* bias2 = (const float*)d_in[14];
    const float* lin_w = (const float*)d_in[15];
    const float* lin_b = (const float*)d_in[16];
    float* out = (float*)d_out;

    const int N = in_sizes[0] / 64;
    const int E = in_sizes[1] / 2;
    const int G = out_size / 32;
    const int* src = ei;
    const int* dst = ei + E;

    // ---- workspace carve-up (256B-aligned) ----
    char*  ws  = (char*)d_ws;
    size_t off = 0;
    auto alloc = [&](size_t bytes) -> void* {
        void* p = ws + off;
        off += bytes;
        off = (off + 255) & ~(size_t)255;
        return p;
    };
    _Float16* xl   = (_Float16*)alloc((size_t)N * 64 * sizeof(_Float16));
    float* xr      = (float*)alloc((size_t)N * 64 * sizeof(float));
    float* h1      = (float*)alloc((size_t)N * 64 * sizeof(float));  // also h2
    // zeroed region (contiguous): cnt, novf, sums, cnts
    int*   cnt     = (int*)alloc((size_t)N * sizeof(int));
    int*   novf    = (int*)alloc(256);
    float* sums    = (float*)alloc((size_t)G * 64 * sizeof(float));
    float* cnts    = (float*)alloc((size_t)G * sizeof(float));
    char*  zend    = ws + off;
    unsigned short* ell = (unsigned short*)alloc((size_t)N * ELLC * sizeof(unsigned short));
    int*   ovf_dst = (int*)alloc((size_t)OVF_CAP * sizeof(int));
    int*   ovf_src = (int*)alloc((size_t)OVF_CAP * sizeof(int));

    (void)hipMemsetAsync(cnt, 0, (size_t)(zend - (char*)cnt), stream);

    int ggrid  = (N + GROWS - 1) / GROWS;
    int agrid  = (N + 3) / 4;                    // one wave per dst node
    int nchunk = (E + ECHUNK - 1) / ECHUNK;
    int fb     = nchunk * 8;                     // fill virtual blocks (x8 XCD)
    int psize  = (N + 7) / 8;                    // dst partition size
    // interleaved grid: groups of 24 = 16 fill + 8 gemm
    int ngroups = max((fb + 15) / 16, (ggrid + 7) / 8);
    int igrid   = ngroups * 24;

    // ---- interleaved: XCD-partitioned ELL fill + layer-1 dual GEMM ----
    fill_gemm_kernel<<<igrid, 256, 0, stream>>>(
        src, dst, cnt, ell, novf, ovf_dst, ovf_src, E, N, psize, fb, ggrid,
        x, Wl1, bl1, Wr1, br1, xl, xr);

    gat_aggregate_kernel<<<agrid, 256, 0, stream>>>(
        xl, xr, cnt, ell, novf, ovf_dst, ovf_src, att1, bias1, h1, N);

    // ---- layer 2 (gemm2 reads h1, overwrites xl/xr; agg2 rewrites h1) ----
    dual_gemm64_kernel<<<ggrid, 256, 0, stream>>>(h1, Wl2, bl2, Wr2, br2, xl, xr, N);
    gat_aggregate_kernel<<<agrid, 256, 0, stream>>>(
        xl, xr, cnt, ell, novf, ovf_dst, ovf_src, att2, bias2, h1, N);

    // ---- pool + final linear ----
    const int NWAVES = 2048;
    pool_kernel<<<512, 256, 0, stream>>>(h1, batch, sums, cnts, N, NWAVES);
    int total = G * 32;
    final_kernel<<<(total + 255) / 256, 256, 0, stream>>>(sums, cnts, lin_w, lin_b, out, total);
}